// Round 8
// baseline (17555.794 us; speedup 1.0000x reference)
//
#include <hip/hip_runtime.h>
#include <hip/hip_cooperative_groups.h>

namespace cg = cooperative_groups;

#define Bb 64
#define Ss 128
#define Tt 128
#define Ee 512
#define Hh 1024
#define GRID 256
#define NTHR 512
#define GSTRIDE (GRID * NTHR)

using short8 = __attribute__((ext_vector_type(8))) short;
using f32x4  = __attribute__((ext_vector_type(4))) float;
typedef unsigned long long u64;

// ---- ws layout (byte offsets), total ~55.1 MiB ----
#define PK_OFF    0u            // ushort [8192][1024]  proj_key bf16
#define ENC_OFF   16777216u     // ushort [64][128][1024] enc bf16
#define WQF_OFF   33554432u     // frag [64 nt][32 kt][64][8]
#define WHHF_OFF  35651584u     // frag [192 nt][32 kt][64][8] (perm rows)
#define WIHF_OFF  41943040u     // frag [192 nt][48 kt][64][8] (perm rows)
#define WKF_OFF   51380224u     // frag [64 nt][32 kt][64][8]
#define QWS_OFF   53477376u     // float [64][1024]
#define GHWS_OFF  53739520u     // float [192 ntp][64 b][16 jj]
#define CTXF_OFF  54525952u     // frag A [4 btile][32 kt][64][8]  (128 KB)
#define HFRG_OFF  54657024u     // frag A [4 btile][32 kt][64][8]  (128 KB)
#define HPRV_OFF  54788096u     // float [64][1024]
#define FLG_OFF   55050240u     // uint [384][16] barrier flags (1 line each)

__device__ __forceinline__ float fast_tanh(float x) {
  float e = __expf(2.0f * x);
  return 1.0f - __fdividef(2.0f, e + 1.0f);
}
__device__ __forceinline__ float fast_sig(float x) {
  return __fdividef(1.0f, 1.0f + __expf(-x));
}
__device__ __forceinline__ unsigned f2bf(float x) {
  union { float f; unsigned u; } v; v.f = x;
  unsigned r = v.u + 0x7fffu + ((v.u >> 16) & 1u);
  return (r >> 16);
}
__device__ __forceinline__ uint4 pack8(float4 a, float4 b) {
  uint4 u;
  u.x = f2bf(a.x) | (f2bf(a.y) << 16);
  u.y = f2bf(a.z) | (f2bf(a.w) << 16);
  u.z = f2bf(b.x) | (f2bf(b.y) << 16);
  u.w = f2bf(b.z) | (f2bf(b.w) << 16);
  return u;
}
__device__ __forceinline__ void cvt8_store(const float* src, unsigned short* dst) {
  float4 f0 = *(const float4*)src, f1 = *(const float4*)(src + 4);
  *(uint4*)dst = pack8(f0, f1);
}
__device__ __forceinline__ short8 ld_frag(const unsigned short* base, int tile, int lane) {
  return *(const short8*)(base + ((size_t)tile * 64 + lane) * 8);
}
__device__ __forceinline__ short8 cvt8_reg(const float* src) {
  float4 f0 = *(const float4*)src, f1 = *(const float4*)(src + 4);
  union { uint4 u; short8 s; } cv; cv.u = pack8(f0, f1);
  return cv.s;
}
__device__ __forceinline__ void bf8_to_f32(uint4 u, float* f) {
  f[0] = __uint_as_float((u.x & 0xffffu) << 16);
  f[1] = __uint_as_float(u.x & 0xffff0000u);
  f[2] = __uint_as_float((u.y & 0xffffu) << 16);
  f[3] = __uint_as_float(u.y & 0xffff0000u);
  f[4] = __uint_as_float((u.z & 0xffffu) << 16);
  f[5] = __uint_as_float(u.z & 0xffff0000u);
  f[6] = __uint_as_float((u.w & 0xffffu) << 16);
  f[7] = __uint_as_float(u.w & 0xffff0000u);
}

// ---- coherent (device-scope, L2-safe) access helpers ----
__device__ __forceinline__ u64 ld_coh8(const void* p) {
  return __hip_atomic_load((const u64*)p, __ATOMIC_RELAXED, __HIP_MEMORY_SCOPE_AGENT);
}
__device__ __forceinline__ void st_coh8(void* p, u64 v) {
  __hip_atomic_store((u64*)p, v, __ATOMIC_RELAXED, __HIP_MEMORY_SCOPE_AGENT);
}
__device__ __forceinline__ unsigned ld_coh1(const void* p) {
  return __hip_atomic_load((const unsigned*)p, __ATOMIC_RELAXED, __HIP_MEMORY_SCOPE_AGENT);
}
__device__ __forceinline__ void st_coh1(void* p, unsigned v) {
  __hip_atomic_store((unsigned*)p, v, __ATOMIC_RELAXED, __HIP_MEMORY_SCOPE_AGENT);
}
__device__ __forceinline__ void st_coh1f(void* p, float v) {
  union { float f; unsigned u; } c; c.f = v; st_coh1(p, c.u);
}

// custom grid barrier: no L2 flush/invalidate
__device__ __forceinline__ void gbar(unsigned* flags, int k, int tid) {
  asm volatile("s_waitcnt vmcnt(0)" ::: "memory");
  __syncthreads();
  if (tid == 0) {
    unsigned* f = flags + k * 16;
    atomicAdd(f, 1u);
    while (atomicAdd(f, 0u) < (unsigned)GRID) __builtin_amdgcn_s_sleep(16);
  }
  __syncthreads();
}

template <int K, bool PERM>
__device__ void conv_frag(const float* __restrict__ W, unsigned short* __restrict__ F,
                          int gtid, int total) {
  const int kpg = K / 8;
  for (int i = gtid; i < total; i += GSTRIDE) {
    int np = i / kpg, kg = i - np * kpg;
    int row;
    if (PERM) {
      int ntp = np >> 4, jb = ntp / 3, g = ntp - jb * 3;
      row = g * 1024 + jb * 16 + (np & 15);
    } else row = np;
    int k0 = kg * 8;
    int kt = k0 >> 5, quad = (k0 >> 3) & 3;
    int lane_f = (np & 15) | (quad << 4);
    size_t dst = ((size_t)((np >> 4) * (K / 32) + kt) * 64 + lane_f) * 8;
    cvt8_store(W + (size_t)row * K + k0, F + dst);
  }
}

__global__ void __launch_bounds__(NTHR, 2)
bahdanau_kernel(const float* __restrict__ inputs,
                const float* __restrict__ enc,
                const float* __restrict__ finals,
                const float* __restrict__ Wk,
                const float* __restrict__ Wq,
                const float* __restrict__ vatt,
                const float* __restrict__ Wih,
                const float* __restrict__ Whh,
                const float* __restrict__ bih,
                const float* __restrict__ bhh,
                float* __restrict__ dout,
                char* __restrict__ wsb)
{
  cg::grid_group grid = cg::this_grid();
  extern __shared__ char lds[];
  float* smem = (float*)lds;

  const int tid  = threadIdx.x;
  const int bid  = blockIdx.x;
  const int lane = tid & 63;
  const int wv   = __builtin_amdgcn_readfirstlane(tid >> 6);   // 0..7
  const int gtid = bid * NTHR + tid;
  const int quad = lane >> 4, col = lane & 15;

  unsigned short* pk   = (unsigned short*)(wsb + PK_OFF);
  unsigned short* encb = (unsigned short*)(wsb + ENC_OFF);
  unsigned short* wqf  = (unsigned short*)(wsb + WQF_OFF);
  unsigned short* whhf = (unsigned short*)(wsb + WHHF_OFF);
  unsigned short* wihf = (unsigned short*)(wsb + WIHF_OFF);
  unsigned short* wkf  = (unsigned short*)(wsb + WKF_OFF);
  float* qws  = (float*)(wsb + QWS_OFF);
  float* ghws = (float*)(wsb + GHWS_OFF);
  unsigned short* ctxf = (unsigned short*)(wsb + CTXF_OFF);
  unsigned short* hfrg = (unsigned short*)(wsb + HFRG_OFF);
  float* hprv = (float*)(wsb + HPRV_OFF);
  unsigned* flags = (unsigned*)(wsb + FLG_OFF);
  float* hidout = dout;
  float* outs   = dout + Bb * Hh;

  // ================= P0: conversions + flag init (plain; made durable by cg sync) ====
  for (int i = gtid; i < 6144; i += GSTRIDE) flags[i] = 0u;
  for (int i = gtid; i < 1048576; i += GSTRIDE)
    cvt8_store(enc + (size_t)i * 8, encb + (size_t)i * 8);
  conv_frag<1024, false>(Wq,  wqf,  gtid, 131072);
  conv_frag<1024, false>(Wk,  wkf,  gtid, 131072);
  conv_frag<1024, true >(Whh, whhf, gtid, 393216);
  conv_frag<1536, true >(Wih, wihf, gtid, 589824);
  for (int i = gtid; i < 8192; i += GSTRIDE) {
    int b = i >> 7, kg = i & 127, k0 = kg * 8;
    int kt = k0 >> 5, qd = (k0 >> 3) & 3;
    int lf = (b & 15) | (qd << 4);
    cvt8_store(finals + (size_t)b * Hh + k0,
               hfrg + ((size_t)((b >> 4) * 32 + kt) * 64 + lf) * 8);
  }
  for (int i = gtid; i < 16384; i += GSTRIDE)
    ((float4*)hprv)[i] = ((const float4*)finals)[i];
  grid.sync();

  // ================= P0b: proj_key = enc @ Wk^T (MFMA) =================
  {
    const int W = bid * 8 + wv;
    const int mt = W >> 2;
    const int ng = W & 3;
    for (int nt2 = 0; nt2 < 16; ++nt2) {
      int nt = ng * 16 + nt2;
      f32x4 acc = {0.f, 0.f, 0.f, 0.f};
      for (int kt = 0; kt < 32; ++kt) {
        short8 a = *(const short8*)(encb + (size_t)(mt * 16 + col) * Hh + kt * 32 + quad * 8);
        short8 b = ld_frag(wkf, nt * 32 + kt, lane);
        acc = __builtin_amdgcn_mfma_f32_16x16x32_bf16(a, b, acc, 0, 0, 0);
      }
      #pragma unroll
      for (int r = 0; r < 4; ++r)
        pk[(size_t)(mt * 16 + quad * 4 + r) * Hh + nt * 16 + col] = (unsigned short)f2bf(acc[r]);
    }
  }
  grid.sync();

  for (int t = 0; t < Tt; ++t) {
    // ===== Phase A: [q ; gh] = h @ [Wq ; Whh_perm]^T  (64 blocks x 4 ntiles) =====
    if (bid < 64) {
      const int btile = wv & 3;
      const int kh    = wv >> 2;
      // prefetch this wave's 16 A-frags coherently, reuse for all 4 ntiles
      u64 a0[16], a1[16];
      {
        const u64* ab = (const u64*)hfrg
                      + ((size_t)(btile * 32 + kh * 16) * 64 + lane) * 2;
        #pragma unroll
        for (int i = 0; i < 16; ++i) {
          a0[i] = ld_coh8(ab + i * 128);
          a1[i] = ld_coh8(ab + i * 128 + 1);
        }
      }
      float* part = smem;   // [4 nt4][8 wv][64 lane][4]  (32 KB)
      #pragma unroll
      for (int nt4 = 0; nt4 < 4; ++nt4) {
        const unsigned short* bbase = (nt4 == 0) ? wqf : whhf;
        const int btl0 = (nt4 == 0) ? (bid * 32) : ((bid * 3 + nt4 - 1) * 32);
        f32x4 acc = {0.f, 0.f, 0.f, 0.f};
        #pragma unroll
        for (int i = 0; i < 16; ++i) {
          union { u64 q[2]; short8 s; } av; av.q[0] = a0[i]; av.q[1] = a1[i];
          short8 b = ld_frag(bbase, btl0 + kh * 16 + i, lane);
          acc = __builtin_amdgcn_mfma_f32_16x16x32_bf16(av.s, b, acc, 0, 0, 0);
        }
        #pragma unroll
        for (int r = 0; r < 4; ++r)
          part[((nt4 * 8 + wv) * 64 + lane) * 4 + r] = acc[r];
      }
      __syncthreads();
      #pragma unroll
      for (int rep = 0; rep < 8; ++rep) {
        int id = tid + rep * NTHR;          // 0..4095
        int nt4 = id >> 10;
        int rem = id & 1023;
        int bt = rem >> 8, ln = (rem >> 2) & 63, r = rem & 3;
        float v = part[((nt4 * 8 + 0 * 4 + bt) * 64 + ln) * 4 + r]
                + part[((nt4 * 8 + 1 * 4 + bt) * 64 + ln) * 4 + r];
        int qd = ln >> 4, cl = ln & 15;
        int row = bt * 16 + qd * 4 + r;     // batch index b
        if (nt4 == 0) st_coh1f(&qws[(size_t)row * Hh + bid * 16 + cl], v);
        else st_coh1f(&ghws[((size_t)(bid * 3 + nt4 - 1) * 64 + row) * 16 + cl], v);
      }
    }
    gbar(flags, t * 3 + 0, tid);

    // ===== Phase B: attention, one block per b (64 blocks) =====
    if (bid < Bb) {
      const int b = bid;
      float* e_s  = smem;          // 128
      float* al_s = smem + 128;    // 128
      float* comb = smem + 256;    // [4][128][8]
      float qr[16], vr[16];
      {
        const u64* qb = (const u64*)(qws + (size_t)b * Hh + lane * 16);
        union { u64 q[8]; float f[16]; } qu;
        #pragma unroll
        for (int i = 0; i < 8; ++i) qu.q[i] = ld_coh8(qb + i);
        #pragma unroll
        for (int i = 0; i < 16; ++i) qr[i] = qu.f[i];
      }
      #pragma unroll
      for (int i = 0; i < 16; i += 4)
        *(float4*)(vr + i) = *(const float4*)(vatt + lane * 16 + i);
      for (int si = 0; si < 16; ++si) {
        int s = wv * 16 + si;
        const unsigned short* pr = pk + ((size_t)b * Ss + s) * Hh + lane * 16;
        uint4 u0 = *(const uint4*)pr, u1 = *(const uint4*)(pr + 8);
        float pv[16]; bf8_to_f32(u0, pv); bf8_to_f32(u1, pv + 8);
        float p = 0.0f;
        #pragma unroll
        for (int i = 0; i < 16; ++i) p = fmaf(vr[i], fast_tanh(qr[i] + pv[i]), p);
        #pragma unroll
        for (int m = 1; m < 64; m <<= 1) p += __shfl_xor(p, m, 64);
        if (lane == 0) e_s[s] = p;
      }
      __syncthreads();
      if (wv == 0) {
        float x0 = e_s[lane], x1 = e_s[lane + 64];
        float m = fmaxf(x0, x1);
        #pragma unroll
        for (int mm = 1; mm < 64; mm <<= 1) m = fmaxf(m, __shfl_xor(m, mm, 64));
        float ex0 = __expf(x0 - m), ex1 = __expf(x1 - m);
        float ssum = ex0 + ex1;
        #pragma unroll
        for (int mm = 1; mm < 64; mm <<= 1) ssum += __shfl_xor(ssum, mm, 64);
        float inv = __fdividef(1.0f, ssum);
        al_s[lane] = ex0 * inv; al_s[lane + 64] = ex1 * inv;
      }
      __syncthreads();
      {
        int hq = tid & 127, tq = tid >> 7;
        int h0 = hq * 8;
        float c8[8] = {0,0,0,0,0,0,0,0};
        for (int s2 = 0; s2 < 32; ++s2) {
          int s = tq * 32 + s2;
          float al = al_s[s];
          uint4 u = *(const uint4*)(encb + ((size_t)b * Ss + s) * Hh + h0);
          float ev[8]; bf8_to_f32(u, ev);
          #pragma unroll
          for (int i = 0; i < 8; ++i) c8[i] = fmaf(al, ev[i], c8[i]);
        }
        #pragma unroll
        for (int i = 0; i < 8; ++i) comb[(tq * 128 + hq) * 8 + i] = c8[i];
      }
      __syncthreads();
      if (tid < 128) {
        int h0 = tid * 8;
        float f[8];
        #pragma unroll
        for (int i = 0; i < 8; ++i)
          f[i] = comb[tid * 8 + i] + comb[(128 + tid) * 8 + i]
               + comb[(256 + tid) * 8 + i] + comb[(384 + tid) * 8 + i];
        int ktl = h0 >> 5, qd = (h0 >> 3) & 3;
        int lf = (b & 15) | (qd << 4);
        uint4 u = pack8(make_float4(f[0],f[1],f[2],f[3]), make_float4(f[4],f[5],f[6],f[7]));
        unsigned short* dst = ctxf + ((size_t)((b >> 4) * 32 + ktl) * 64 + lf) * 8;
        u64 lo = (u64)u.x | ((u64)u.y << 32);
        u64 hi = (u64)u.z | ((u64)u.w << 32);
        st_coh8(dst, lo); st_coh8(dst + 4, hi);
      }
    }
    gbar(flags, t * 3 + 1, tid);

    // ===== Phase C: gx = [x_t, ctx] @ Wih_perm^T + gates (64 blocks) =====
    if (bid < 64) {
      const int jp = bid >> 2;            // 0..15 (64 j's each)
      const int bq = bid & 3;             // btile (16 b's)
      // stage this btile's ctx slice (32 KB) into LDS coherently
      {
        u64* l8 = (u64*)lds;
        const u64* g8 = (const u64*)(ctxf + (size_t)bq * 32 * 64 * 8);
        u64 r[8];
        #pragma unroll
        for (int i = 0; i < 8; ++i) r[i] = ld_coh8(g8 + tid + i * NTHR);
        #pragma unroll
        for (int i = 0; i < 8; ++i) l8[tid + i * NTHR] = r[i];
      }
      __syncthreads();
      float* gxl = (float*)(lds + 32768);  // [24 slot][64 lane][4]  (24 KB)
      const int kh = wv & 1;               // slot parity == wave parity
      short8 xa[16];
      if (kh == 0) {
        const float* xrow = inputs + ((size_t)(bq * 16 + col) * Tt + t) * Ee + quad * 8;
        #pragma unroll
        for (int i = 0; i < 16; ++i) xa[i] = cvt8_reg(xrow + i * 32);
      }
      const unsigned short* lctx = (const unsigned short*)lds;
      #pragma unroll
      for (int task = 0; task < 3; ++task) {
        int slot = wv + task * 8;
        int ntp = jp * 12 + (slot >> 1);
        f32x4 acc = {0.f, 0.f, 0.f, 0.f};
        #pragma unroll
        for (int k2 = 0; k2 < 24; ++k2) {
          int kt = kh * 24 + k2;
          short8 a;
          if (kh == 0 && k2 < 16) a = xa[k2];
          else a = *(const short8*)(lctx + ((size_t)(kt - 16) * 64 + lane) * 8);
          short8 bfr = ld_frag(wihf, ntp * 48 + kt, lane);
          acc = __builtin_amdgcn_mfma_f32_16x16x32_bf16(a, bfr, acc, 0, 0, 0);
        }
        #pragma unroll
        for (int r = 0; r < 4; ++r) gxl[(slot * 64 + lane) * 4 + r] = acc[r];
      }
      __syncthreads();
      {
        int bloc = tid >> 5;                // 0..15
        int jpair = tid & 31;               // 0..31
        int b = bq * 16 + bloc;
        int j0p = jp * 64 + jpair * 2;
        int jj2 = (jpair * 2) >> 4;         // local jb 0..3
        int jb = jp * 4 + jj2;
        int qd = bloc >> 2, r = bloc & 3;
        u64 g0 = ld_coh8(&ghws[((size_t)(jb * 3 + 0) * 64 + b) * 16 + (j0p & 15)]);
        u64 g1 = ld_coh8(&ghws[((size_t)(jb * 3 + 1) * 64 + b) * 16 + (j0p & 15)]);
        u64 g2 = ld_coh8(&ghws[((size_t)(jb * 3 + 2) * 64 + b) * 16 + (j0p & 15)]);
        u64 hpu = ld_coh8(&hprv[(size_t)b * Hh + j0p]);
        float hn2[2];
        #pragma unroll
        for (int jj = 0; jj < 2; ++jj) {
          int j = j0p + jj;
          int cl = j & 15;
          int ll = (qd << 4) | cl;
          int sb = (jj2 * 3) * 2;           // slot base for this jb
          float gx0 = gxl[(((sb + 0)) * 64 + ll) * 4 + r] + gxl[(((sb + 1)) * 64 + ll) * 4 + r];
          float gx1 = gxl[(((sb + 2)) * 64 + ll) * 4 + r] + gxl[(((sb + 3)) * 64 + ll) * 4 + r];
          float gx2 = gxl[(((sb + 4)) * 64 + ll) * 4 + r] + gxl[(((sb + 5)) * 64 + ll) * 4 + r];
          float gh0 = __uint_as_float((unsigned)(jj ? (g0 >> 32) : g0));
          float gh1 = __uint_as_float((unsigned)(jj ? (g1 >> 32) : g1));
          float gh2 = __uint_as_float((unsigned)(jj ? (g2 >> 32) : g2));
          float hp  = __uint_as_float((unsigned)(jj ? (hpu >> 32) : hpu));
          float rr = fast_sig(gx0 + bih[0 * 1024 + j] + gh0 + bhh[0 * 1024 + j]);
          float zz = fast_sig(gx1 + bih[1 * 1024 + j] + gh1 + bhh[1 * 1024 + j]);
          float nn = fast_tanh(gx2 + bih[2 * 1024 + j] + rr * (gh2 + bhh[2 * 1024 + j]));
          hn2[jj] = (1.0f - zz) * nn + zz * hp;
        }
        *(float2*)(outs + ((size_t)b * Tt + t) * Hh + j0p) = make_float2(hn2[0], hn2[1]);
        u64 hpv = (u64)__float_as_uint(hn2[0]) | ((u64)__float_as_uint(hn2[1]) << 32);
        st_coh8(&hprv[(size_t)b * Hh + j0p], hpv);
        int kt = j0p >> 5, qd2 = (j0p >> 3) & 3;
        int lfh = (b & 15) | (qd2 << 4);
        unsigned hw = f2bf(hn2[0]) | (f2bf(hn2[1]) << 16);
        st_coh1(hfrg + ((size_t)(bq * 32 + kt) * 64 + lfh) * 8 + (j0p & 7), hw);
      }
    }
    gbar(flags, t * 3 + 2, tid);
  }

  // final hidden from hprv (coherent)
  {
    int idx = gtid;
    if (idx < Bb * Hh) {
      unsigned u = ld_coh1(&hprv[idx]);
      hidout[idx] = __uint_as_float(u);
    }
  }
}

extern "C" void kernel_launch(void* const* d_in, const int* in_sizes, int n_in,
                              void* d_out, int out_size, void* d_ws, size_t ws_size,
                              hipStream_t stream) {
  const float* inputs = (const float*)d_in[0];
  const float* enc    = (const float*)d_in[1];
  const float* finals = (const float*)d_in[2];
  const float* Wk  = (const float*)d_in[4];
  const float* Wq  = (const float*)d_in[5];
  const float* v   = (const float*)d_in[6];
  const float* Wih = (const float*)d_in[7];
  const float* Whh = (const float*)d_in[8];
  const float* bih = (const float*)d_in[9];
  const float* bhh = (const float*)d_in[10];
  float* out = (float*)d_out;
  char* ws   = (char*)d_ws;   // needs ~55.2 MB

  void* args[] = {(void*)&inputs, (void*)&enc, (void*)&finals, (void*)&Wk,
                  (void*)&Wq, (void*)&v, (void*)&Wih, (void*)&Whh,
                  (void*)&bih, (void*)&bhh, (void*)&out, (void*)&ws};
  (void)hipLaunchCooperativeKernel((const void*)bahdanau_kernel,
                                   dim3(GRID), dim3(NTHR), args, 65536, stream);
}

// Round 9
// 10817.578 us; speedup vs baseline: 1.6229x; 1.6229x over previous
//
#include <hip/hip_runtime.h>
#include <hip/hip_cooperative_groups.h>

namespace cg = cooperative_groups;

#define Bb 64
#define Ss 128
#define Tt 128
#define Ee 512
#define Hh 1024
#define GRID 256
#define NTHR 512
#define GSTRIDE (GRID * NTHR)

using short8 = __attribute__((ext_vector_type(8))) short;
using f32x4  = __attribute__((ext_vector_type(4))) float;
typedef unsigned long long u64;

// ---- ws layout (byte offsets), total ~55.1 MiB ----
#define PK_OFF    0u            // ushort [8192][1024]  proj_key bf16
#define ENC_OFF   16777216u     // ushort [64][128][1024] enc bf16
#define WQF_OFF   33554432u     // frag [64 nt][32 kt][64][8]
#define WHHF_OFF  35651584u     // frag [192 nt][32 kt][64][8] (perm rows)
#define WIHF_OFF  41943040u     // frag [192 nt][48 kt][64][8] (perm rows)
#define WKF_OFF   51380224u     // frag [64 nt][32 kt][64][8] (dead after P0b)
#define QW2_OFF   51380224u     // float [2][64][1024]  (aliases wkf; 512 KB)
#define GH2_OFF   51904512u     // float [2][192][64][16] (1.5 MB)
#define CTXF_OFF  54525952u     // frag A [4 btile][32 kt][64][8]  (128 KB)
#define HFRG_OFF  54657024u     // frag A [4 btile][32 kt][64][8]  (128 KB)
#define HPRV_OFF  54788096u     // float [64][1024]
#define FLG_OFF   55050240u     // uint [384][16] barrier flags

__device__ __forceinline__ float fast_tanh(float x) {
  float e = __expf(2.0f * x);
  return 1.0f - __fdividef(2.0f, e + 1.0f);
}
__device__ __forceinline__ float fast_sig(float x) {
  return __fdividef(1.0f, 1.0f + __expf(-x));
}
__device__ __forceinline__ unsigned f2bf(float x) {
  union { float f; unsigned u; } v; v.f = x;
  unsigned r = v.u + 0x7fffu + ((v.u >> 16) & 1u);
  return (r >> 16);
}
__device__ __forceinline__ uint4 pack8(float4 a, float4 b) {
  uint4 u;
  u.x = f2bf(a.x) | (f2bf(a.y) << 16);
  u.y = f2bf(a.z) | (f2bf(a.w) << 16);
  u.z = f2bf(b.x) | (f2bf(b.y) << 16);
  u.w = f2bf(b.z) | (f2bf(b.w) << 16);
  return u;
}
__device__ __forceinline__ void cvt8_store(const float* src, unsigned short* dst) {
  float4 f0 = *(const float4*)src, f1 = *(const float4*)(src + 4);
  *(uint4*)dst = pack8(f0, f1);
}
__device__ __forceinline__ short8 ld_frag(const unsigned short* base, int tile, int lane) {
  return *(const short8*)(base + ((size_t)tile * 64 + lane) * 8);
}
__device__ __forceinline__ short8 cvt8_reg(const float* src) {
  float4 f0 = *(const float4*)src, f1 = *(const float4*)(src + 4);
  union { uint4 u; short8 s; } cv; cv.u = pack8(f0, f1);
  return cv.s;
}
__device__ __forceinline__ void bf8_to_f32(uint4 u, float* f) {
  f[0] = __uint_as_float((u.x & 0xffffu) << 16);
  f[1] = __uint_as_float(u.x & 0xffff0000u);
  f[2] = __uint_as_float((u.y & 0xffffu) << 16);
  f[3] = __uint_as_float(u.y & 0xffff0000u);
  f[4] = __uint_as_float((u.z & 0xffffu) << 16);
  f[5] = __uint_as_float(u.z & 0xffff0000u);
  f[6] = __uint_as_float((u.w & 0xffffu) << 16);
  f[7] = __uint_as_float(u.w & 0xffff0000u);
}

// ---- coherent (device-scope) access helpers ----
__device__ __forceinline__ u64 ld_coh8(const void* p) {
  return __hip_atomic_load((const u64*)p, __ATOMIC_RELAXED, __HIP_MEMORY_SCOPE_AGENT);
}
__device__ __forceinline__ void st_coh8(void* p, u64 v) {
  __hip_atomic_store((u64*)p, v, __ATOMIC_RELAXED, __HIP_MEMORY_SCOPE_AGENT);
}
__device__ __forceinline__ unsigned ld_coh1(const void* p) {
  return __hip_atomic_load((const unsigned*)p, __ATOMIC_RELAXED, __HIP_MEMORY_SCOPE_AGENT);
}
__device__ __forceinline__ void st_coh1(void* p, unsigned v) {
  __hip_atomic_store((unsigned*)p, v, __ATOMIC_RELAXED, __HIP_MEMORY_SCOPE_AGENT);
}
__device__ __forceinline__ void st_coh1f(void* p, float v) {
  union { float f; unsigned u; } c; c.f = v; st_coh1(p, c.u);
}
__device__ __forceinline__ float u2f(unsigned u) { return __uint_as_float(u); }

// custom grid barrier: no L2 flush/invalidate
__device__ __forceinline__ void gbar(unsigned* flags, int k, int tid) {
  asm volatile("s_waitcnt vmcnt(0)" ::: "memory");
  __syncthreads();
  if (tid == 0) {
    unsigned* f = flags + k * 16;
    atomicAdd(f, 1u);
    while (atomicAdd(f, 0u) < (unsigned)GRID) __builtin_amdgcn_s_sleep(8);
  }
  __syncthreads();
}

template <int K, bool PERM>
__device__ void conv_frag(const float* __restrict__ W, unsigned short* __restrict__ F,
                          int gtid, int total) {
  const int kpg = K / 8;
  for (int i = gtid; i < total; i += GSTRIDE) {
    int np = i / kpg, kg = i - np * kpg;
    int row;
    if (PERM) {
      int ntp = np >> 4, jb = ntp / 3, g = ntp - jb * 3;
      row = g * 1024 + jb * 16 + (np & 15);
    } else row = np;
    int k0 = kg * 8;
    int kt = k0 >> 5, quad = (k0 >> 3) & 3;
    int lane_f = (np & 15) | (quad << 4);
    size_t dst = ((size_t)((np >> 4) * (K / 32) + kt) * 64 + lane_f) * 8;
    cvt8_store(W + (size_t)row * K + k0, F + dst);
  }
}

__global__ void __launch_bounds__(NTHR, 2)
bahdanau_kernel(const float* __restrict__ inputs,
                const float* __restrict__ enc,
                const float* __restrict__ finals,
                const float* __restrict__ Wk,
                const float* __restrict__ Wq,
                const float* __restrict__ vatt,
                const float* __restrict__ Wih,
                const float* __restrict__ Whh,
                const float* __restrict__ bih,
                const float* __restrict__ bhh,
                float* __restrict__ dout,
                char* __restrict__ wsb)
{
  cg::grid_group grid = cg::this_grid();
  extern __shared__ char lds[];
  float* smem = (float*)lds;

  const int tid  = threadIdx.x;
  const int bid  = blockIdx.x;
  const int lane = tid & 63;
  const int wv   = __builtin_amdgcn_readfirstlane(tid >> 6);   // 0..7
  const int gtid = bid * NTHR + tid;
  const int quad = lane >> 4, col = lane & 15;

  unsigned short* pk   = (unsigned short*)(wsb + PK_OFF);
  unsigned short* encb = (unsigned short*)(wsb + ENC_OFF);
  unsigned short* wqf  = (unsigned short*)(wsb + WQF_OFF);
  unsigned short* whhf = (unsigned short*)(wsb + WHHF_OFF);
  unsigned short* wihf = (unsigned short*)(wsb + WIHF_OFF);
  unsigned short* wkf  = (unsigned short*)(wsb + WKF_OFF);
  float* qws2 = (float*)(wsb + QW2_OFF);   // [2][64][1024]
  float* ghw2 = (float*)(wsb + GH2_OFF);   // [2][192][64][16]
  unsigned short* ctxf = (unsigned short*)(wsb + CTXF_OFF);
  unsigned short* hfrg = (unsigned short*)(wsb + HFRG_OFF);
  float* hprv = (float*)(wsb + HPRV_OFF);
  unsigned* flags = (unsigned*)(wsb + FLG_OFF);
  float* hidout = dout;
  float* outs   = dout + Bb * Hh;

  // ================= P0: conversions + flag init =================
  for (int i = gtid; i < 6144; i += GSTRIDE) flags[i] = 0u;
  for (int i = gtid; i < 1048576; i += GSTRIDE)
    cvt8_store(enc + (size_t)i * 8, encb + (size_t)i * 8);
  conv_frag<1024, false>(Wq,  wqf,  gtid, 131072);
  conv_frag<1024, false>(Wk,  wkf,  gtid, 131072);
  conv_frag<1024, true >(Whh, whhf, gtid, 393216);
  conv_frag<1536, true >(Wih, wihf, gtid, 589824);
  for (int i = gtid; i < 8192; i += GSTRIDE) {
    int b = i >> 7, kg = i & 127, k0 = kg * 8;
    int kt = k0 >> 5, qd = (k0 >> 3) & 3;
    int lf = (b & 15) | (qd << 4);
    cvt8_store(finals + (size_t)b * Hh + k0,
               hfrg + ((size_t)((b >> 4) * 32 + kt) * 64 + lf) * 8);
  }
  for (int i = gtid; i < 16384; i += GSTRIDE)
    ((float4*)hprv)[i] = ((const float4*)finals)[i];
  grid.sync();

  // ================= P0b: proj_key = enc @ Wk^T (MFMA) =================
  {
    const int W = bid * 8 + wv;
    const int mt = W >> 2;
    const int ng = W & 3;
    for (int nt2 = 0; nt2 < 16; ++nt2) {
      int nt = ng * 16 + nt2;
      f32x4 acc = {0.f, 0.f, 0.f, 0.f};
      for (int kt = 0; kt < 32; ++kt) {
        short8 a = *(const short8*)(encb + (size_t)(mt * 16 + col) * Hh + kt * 32 + quad * 8);
        short8 b = ld_frag(wkf, nt * 32 + kt, lane);
        acc = __builtin_amdgcn_mfma_f32_16x16x32_bf16(a, b, acc, 0, 0, 0);
      }
      #pragma unroll
      for (int r = 0; r < 4; ++r)
        pk[(size_t)(mt * 16 + quad * 4 + r) * Hh + nt * 16 + col] = (unsigned short)f2bf(acc[r]);
    }
  }
  grid.sync();   // wkf dead from here; qws2/ghw2 alias it

  for (int t = 0; t < Tt; ++t) {
    // ===== Phase A: [q;gh] partials, 2-way K-split (256 blocks = 128 ng x 2 kh) =====
    {
      const int ng = bid >> 1;            // ntile pair {2ng, 2ng+1}
      const int kh = bid & 1;             // K-half
      // stage h-half (64 frags = 64 KB) into LDS, deduped across waves
      {
        u64* l8 = (u64*)lds;
        const u64* g8 = (const u64*)hfrg;
        u64 r[16];
        #pragma unroll
        for (int i = 0; i < 16; ++i) {
          int id = tid + i * NTHR;        // 0..8191
          int f  = id >> 7;               // local frag 0..63
          int w  = id & 127;              // u64 within frag
          int bt = f >> 4, kt = f & 15;
          r[i] = ld_coh8(g8 + (size_t)(bt * 32 + kh * 16 + kt) * 128 + w);
        }
        #pragma unroll
        for (int i = 0; i < 16; ++i) l8[tid + i * NTHR] = r[i];
      }
      __syncthreads();
      const int btile = wv & 3;
      const int nth   = wv >> 2;
      const int nt    = 2 * ng + nth;
      const bool isq  = (nt < 64);
      const unsigned short* bbase = isq ? wqf : whhf;
      const int btl0 = (isq ? nt * 32 : (nt - 64) * 32) + kh * 16;
      const unsigned short* lfr = (const unsigned short*)lds;
      f32x4 acc = {0.f, 0.f, 0.f, 0.f};
      #pragma unroll
      for (int i = 0; i < 16; ++i) {
        short8 a = *(const short8*)(lfr + ((size_t)(btile * 16 + i) * 64 + lane) * 8);
        short8 b = ld_frag(bbase, btl0 + i, lane);
        acc = __builtin_amdgcn_mfma_f32_16x16x32_bf16(a, b, acc, 0, 0, 0);
      }
      // write partials coherently (no intra-block combine needed)
      #pragma unroll
      for (int r = 0; r < 4; ++r) {
        int brow = btile * 16 + quad * 4 + r;
        if (isq)
          st_coh1f(&qws2[(size_t)kh * 65536 + (size_t)brow * Hh + nt * 16 + col], acc[r]);
        else
          st_coh1f(&ghw2[(size_t)kh * 196608 + ((size_t)(nt - 64) * 64 + brow) * 16 + col], acc[r]);
      }
    }
    gbar(flags, t * 3 + 0, tid);

    // ===== Phase B: attention, one block per b (64 blocks) =====
    if (bid < Bb) {
      const int b = bid;
      float* e_s  = smem;          // 128
      float* al_s = smem + 128;    // 128
      float* comb = smem + 256;    // [4][128][8]
      float qr[16], vr[16];
      {
        const u64* q0 = (const u64*)(qws2 + (size_t)b * Hh + lane * 16);
        const u64* q1 = (const u64*)(qws2 + 65536 + (size_t)b * Hh + lane * 16);
        union { u64 q[8]; float f[16]; } u0, u1;
        #pragma unroll
        for (int i = 0; i < 8; ++i) { u0.q[i] = ld_coh8(q0 + i); u1.q[i] = ld_coh8(q1 + i); }
        #pragma unroll
        for (int i = 0; i < 16; ++i) qr[i] = u0.f[i] + u1.f[i];
      }
      #pragma unroll
      for (int i = 0; i < 16; i += 4)
        *(float4*)(vr + i) = *(const float4*)(vatt + lane * 16 + i);
      for (int si = 0; si < 16; ++si) {
        int s = wv * 16 + si;
        const unsigned short* pr = pk + ((size_t)b * Ss + s) * Hh + lane * 16;
        uint4 u0 = *(const uint4*)pr, u1 = *(const uint4*)(pr + 8);
        float pv[16]; bf8_to_f32(u0, pv); bf8_to_f32(u1, pv + 8);
        float p = 0.0f;
        #pragma unroll
        for (int i = 0; i < 16; ++i) p = fmaf(vr[i], fast_tanh(qr[i] + pv[i]), p);
        #pragma unroll
        for (int m = 1; m < 64; m <<= 1) p += __shfl_xor(p, m, 64);
        if (lane == 0) e_s[s] = p;
      }
      __syncthreads();
      if (wv == 0) {
        float x0 = e_s[lane], x1 = e_s[lane + 64];
        float m = fmaxf(x0, x1);
        #pragma unroll
        for (int mm = 1; mm < 64; mm <<= 1) m = fmaxf(m, __shfl_xor(m, mm, 64));
        float ex0 = __expf(x0 - m), ex1 = __expf(x1 - m);
        float ssum = ex0 + ex1;
        #pragma unroll
        for (int mm = 1; mm < 64; mm <<= 1) ssum += __shfl_xor(ssum, mm, 64);
        float inv = __fdividef(1.0f, ssum);
        al_s[lane] = ex0 * inv; al_s[lane + 64] = ex1 * inv;
      }
      __syncthreads();
      {
        int hq = tid & 127, tq = tid >> 7;
        int h0 = hq * 8;
        float c8[8] = {0,0,0,0,0,0,0,0};
        for (int s2 = 0; s2 < 32; ++s2) {
          int s = tq * 32 + s2;
          float al = al_s[s];
          uint4 u = *(const uint4*)(encb + ((size_t)b * Ss + s) * Hh + h0);
          float ev[8]; bf8_to_f32(u, ev);
          #pragma unroll
          for (int i = 0; i < 8; ++i) c8[i] = fmaf(al, ev[i], c8[i]);
        }
        #pragma unroll
        for (int i = 0; i < 8; ++i) comb[(tq * 128 + hq) * 8 + i] = c8[i];
      }
      __syncthreads();
      if (tid < 128) {
        int h0 = tid * 8;
        float f[8];
        #pragma unroll
        for (int i = 0; i < 8; ++i)
          f[i] = comb[tid * 8 + i] + comb[(128 + tid) * 8 + i]
               + comb[(256 + tid) * 8 + i] + comb[(384 + tid) * 8 + i];
        int ktl = h0 >> 5, qd = (h0 >> 3) & 3;
        int lf = (b & 15) | (qd << 4);
        uint4 u = pack8(make_float4(f[0],f[1],f[2],f[3]), make_float4(f[4],f[5],f[6],f[7]));
        unsigned short* dst = ctxf + ((size_t)((b >> 4) * 32 + ktl) * 64 + lf) * 8;
        u64 lo = (u64)u.x | ((u64)u.y << 32);
        u64 hi = (u64)u.z | ((u64)u.w << 32);
        st_coh8(dst, lo); st_coh8(dst + 4, hi);
      }
    }
    gbar(flags, t * 3 + 1, tid);

    // ===== Phase C: gx = [x_t, ctx] @ Wih_perm^T + gates (256 blocks) =====
    {
      const int jb = bid >> 2;            // 0..63 (16 j's each)
      const int bq = bid & 3;             // btile (16 b's)
      // stage this btile's ctx slice (32 KB) into LDS coherently
      {
        u64* l8 = (u64*)lds;
        const u64* g8 = (const u64*)(ctxf + (size_t)bq * 32 * 64 * 8);
        u64 r[8];
        #pragma unroll
        for (int i = 0; i < 8; ++i) r[i] = ld_coh8(g8 + tid + i * NTHR);
        #pragma unroll
        for (int i = 0; i < 8; ++i) l8[tid + i * NTHR] = r[i];
      }
      __syncthreads();
      float* gxl = (float*)(lds + 32768);  // [6 wv][64 lane][4]
      if (wv < 6) {
        const int g  = wv >> 1;
        const int kh = wv & 1;
        const int ntp = jb * 3 + g;
        const unsigned short* lctx = (const unsigned short*)lds;
        f32x4 acc = {0.f, 0.f, 0.f, 0.f};
        for (int k2 = 0; k2 < 24; ++k2) {
          int kt = kh * 24 + k2;
          short8 a;
          if (kt < 16) {
            int brow = bq * 16 + col;
            a = cvt8_reg(inputs + ((size_t)brow * Tt + t) * Ee + kt * 32 + quad * 8);
          } else {
            a = *(const short8*)(lctx + ((size_t)(kt - 16) * 64 + lane) * 8);
          }
          short8 bfr = ld_frag(wihf, ntp * 48 + kt, lane);
          acc = __builtin_amdgcn_mfma_f32_16x16x32_bf16(a, bfr, acc, 0, 0, 0);
        }
        #pragma unroll
        for (int r = 0; r < 4; ++r) gxl[((wv * 64) + lane) * 4 + r] = acc[r];
      }
      __syncthreads();
      if (tid < 128) {
        int bloc = tid >> 3, jp = tid & 7;
        int b = bq * 16 + bloc;
        int j0p = jb * 16 + jp * 2;
        int qd = bloc >> 2, r = bloc & 3;
        size_t i0 = ((size_t)(jb * 3 + 0) * 64 + b) * 16 + jp * 2;
        size_t i1 = ((size_t)(jb * 3 + 1) * 64 + b) * 16 + jp * 2;
        size_t i2 = ((size_t)(jb * 3 + 2) * 64 + b) * 16 + jp * 2;
        u64 g0a = ld_coh8(&ghw2[i0]), g0b = ld_coh8(&ghw2[196608 + i0]);
        u64 g1a = ld_coh8(&ghw2[i1]), g1b = ld_coh8(&ghw2[196608 + i1]);
        u64 g2a = ld_coh8(&ghw2[i2]), g2b = ld_coh8(&ghw2[196608 + i2]);
        u64 hpu = ld_coh8(&hprv[(size_t)b * Hh + j0p]);
        float hn2[2];
        #pragma unroll
        for (int jj = 0; jj < 2; ++jj) {
          int j = j0p + jj;
          int cl = jp * 2 + jj;
          int ll = (qd << 4) | cl;
          float gx0 = gxl[(0 * 64 + ll) * 4 + r] + gxl[(1 * 64 + ll) * 4 + r];
          float gx1 = gxl[(2 * 64 + ll) * 4 + r] + gxl[(3 * 64 + ll) * 4 + r];
          float gx2 = gxl[(4 * 64 + ll) * 4 + r] + gxl[(5 * 64 + ll) * 4 + r];
          float gh0 = u2f((unsigned)(jj ? (g0a >> 32) : g0a)) + u2f((unsigned)(jj ? (g0b >> 32) : g0b));
          float gh1 = u2f((unsigned)(jj ? (g1a >> 32) : g1a)) + u2f((unsigned)(jj ? (g1b >> 32) : g1b));
          float gh2 = u2f((unsigned)(jj ? (g2a >> 32) : g2a)) + u2f((unsigned)(jj ? (g2b >> 32) : g2b));
          float hp  = u2f((unsigned)(jj ? (hpu >> 32) : hpu));
          float rr = fast_sig(gx0 + bih[0 * 1024 + j] + gh0 + bhh[0 * 1024 + j]);
          float zz = fast_sig(gx1 + bih[1 * 1024 + j] + gh1 + bhh[1 * 1024 + j]);
          float nn = fast_tanh(gx2 + bih[2 * 1024 + j] + rr * (gh2 + bhh[2 * 1024 + j]));
          hn2[jj] = (1.0f - zz) * nn + zz * hp;
        }
        *(float2*)(outs + ((size_t)b * Tt + t) * Hh + j0p) = make_float2(hn2[0], hn2[1]);
        u64 hpv = (u64)__float_as_uint(hn2[0]) | ((u64)__float_as_uint(hn2[1]) << 32);
        st_coh8(&hprv[(size_t)b * Hh + j0p], hpv);
        int kt = j0p >> 5, qd2 = (j0p >> 3) & 3;
        int lfh = (b & 15) | (qd2 << 4);
        unsigned hw = f2bf(hn2[0]) | (f2bf(hn2[1]) << 16);
        st_coh1(hfrg + ((size_t)(bq * 32 + kt) * 64 + lfh) * 8 + (j0p & 7), hw);
      }
    }
    gbar(flags, t * 3 + 2, tid);
  }

  // final hidden from hprv (coherent)
  {
    int idx = gtid;
    if (idx < Bb * Hh) {
      unsigned u = ld_coh1(&hprv[idx]);
      hidout[idx] = __uint_as_float(u);
    }
  }
}

extern "C" void kernel_launch(void* const* d_in, const int* in_sizes, int n_in,
                              void* d_out, int out_size, void* d_ws, size_t ws_size,
                              hipStream_t stream) {
  const float* inputs = (const float*)d_in[0];
  const float* enc    = (const float*)d_in[1];
  const float* finals = (const float*)d_in[2];
  const float* Wk  = (const float*)d_in[4];
  const float* Wq  = (const float*)d_in[5];
  const float* v   = (const float*)d_in[6];
  const float* Wih = (const float*)d_in[7];
  const float* Whh = (const float*)d_in[8];
  const float* bih = (const float*)d_in[9];
  const float* bhh = (const float*)d_in[10];
  float* out = (float*)d_out;
  char* ws   = (char*)d_ws;   // needs ~55.2 MB

  void* args[] = {(void*)&inputs, (void*)&enc, (void*)&finals, (void*)&Wk,
                  (void*)&Wq, (void*)&v, (void*)&Wih, (void*)&Whh,
                  (void*)&bih, (void*)&bhh, (void*)&out, (void*)&ws};
  (void)hipLaunchCooperativeKernel((const void*)bahdanau_kernel,
                                   dim3(GRID), dim3(NTHR), args, 65536, stream);
}